// Round 1
// baseline (6103.593 us; speedup 1.0000x reference)
//
#include <hip/hip_runtime.h>

// ---- problem constants ----
#define MDIM 8192
#define KTOK 32
#define TOK 33            // K + G
#define CDIM 256
#define HEADS 8
#define DHEAD 32
#define NPTS (MDIM * KTOK)          // 262144
#define TTOT (MDIM * TOK)           // 270336
#define HIDD 1024
#define NEI 27
#define POS_BND 25
#define RPE_NUM 51                  // 2*POS_BND+1
#define NCOUT ((long)NPTS * CDIM)   // offset of rt_out in d_out

typedef __bf16 bf16x8 __attribute__((ext_vector_type(8)));
typedef float f32x4 __attribute__((ext_vector_type(4)));

__device__ __forceinline__ unsigned short f2bf(float f) {
    unsigned u = __float_as_uint(f);
    u += 0x7FFFu + ((u >> 16) & 1u);      // round-to-nearest-even
    return (unsigned short)(u >> 16);
}
__device__ __forceinline__ float bf2f(unsigned short s) {
    return __uint_as_float(((unsigned)s) << 16);
}

// ---- weight transpose + bf16 cast: W[Kd][Od] -> Wt[Od][Kd] ----
__global__ void k_wt(const float* __restrict__ W, unsigned short* __restrict__ Wt,
                     int Kd, int Od) {
    int i = blockIdx.x * 256 + threadIdx.x;
    if (i >= Kd * Od) return;
    int o = i / Kd, k = i - o * Kd;
    Wt[i] = f2bf(W[(long)k * Od + o]);
}

// ---- CPE gather + concat(rt) + LN1 -> X (fp32 residual), H (bf16 LN'd) ----
__global__ __launch_bounds__(256) void k_cpe_ln1(
    const float* __restrict__ data, const float* __restrict__ rt,
    const int* __restrict__ neighbors,
    const float* __restrict__ cpe_w, const float* __restrict__ cpe_scale,
    const float* __restrict__ cpe_bias,
    const float* __restrict__ g, const float* __restrict__ b,
    float* __restrict__ X, unsigned short* __restrict__ H) {
    const int t = blockIdx.x;
    const int c = threadIdx.x;
    const int m = t / TOK;
    const int q = t - m * TOK;
    __shared__ int nb[NEI];
    __shared__ float sb[2][4];
    float val;
    if (q == 0) {                       // block-uniform branch
        val = rt[(long)m * CDIM + c];
    } else {
        const int n = m * KTOK + (q - 1);
        if (c < NEI) nb[c] = neighbors[(long)n * NEI + c];
        __syncthreads();
        float acc = 0.f;
        #pragma unroll
        for (int j = 0; j < NEI; ++j)
            acc += data[(long)nb[j] * CDIM + c] * cpe_w[j * CDIM + c];
        val = data[(long)n * CDIM + c] + acc * cpe_scale[c] + cpe_bias[c];
    }
    // block-wide mean/var over 256 channels (1 thread = 1 channel)
    float s = val, s2 = val * val;
    #pragma unroll
    for (int o = 32; o; o >>= 1) { s += __shfl_xor(s, o); s2 += __shfl_xor(s2, o); }
    const int wid = threadIdx.x >> 6;
    if ((threadIdx.x & 63) == 0) { sb[0][wid] = s; sb[1][wid] = s2; }
    __syncthreads();
    const float tot  = sb[0][0] + sb[0][1] + sb[0][2] + sb[0][3];
    const float tot2 = sb[1][0] + sb[1][1] + sb[1][2] + sb[1][3];
    const float mean = tot * (1.f / CDIM);
    const float var  = tot2 * (1.f / CDIM) - mean * mean;
    const float rs   = rsqrtf(var + 1e-5f);
    X[(long)t * CDIM + c] = val;
    H[(long)t * CDIM + c] = f2bf((val - mean) * rs * g[c] + b[c]);
}

// ---- LN2: X -> H (bf16) ----
__global__ __launch_bounds__(256) void k_ln(
    const float* __restrict__ X, const float* __restrict__ g,
    const float* __restrict__ b, unsigned short* __restrict__ H) {
    const int t = blockIdx.x;
    const int c = threadIdx.x;
    const float val = X[(long)t * CDIM + c];
    __shared__ float sb[2][4];
    float s = val, s2 = val * val;
    #pragma unroll
    for (int o = 32; o; o >>= 1) { s += __shfl_xor(s, o); s2 += __shfl_xor(s2, o); }
    const int wid = threadIdx.x >> 6;
    if ((threadIdx.x & 63) == 0) { sb[0][wid] = s; sb[1][wid] = s2; }
    __syncthreads();
    const float tot  = sb[0][0] + sb[0][1] + sb[0][2] + sb[0][3];
    const float tot2 = sb[1][0] + sb[1][1] + sb[1][2] + sb[1][3];
    const float mean = tot * (1.f / CDIM);
    const float var  = tot2 * (1.f / CDIM) - mean * mean;
    const float rs   = rsqrtf(var + 1e-5f);
    H[(long)t * CDIM + c] = f2bf((val - mean) * rs * g[c] + b[c]);
}

// ---- bf16 MFMA GEMM: D[T x Odim] = A[T x KDIM] @ Wt[Odim x KDIM]^T + bias ----
// EPI 0: store bf16            (qkv)
// EPI 1: X += D (fp32, in-place residual)   (proj)
// EPI 2: gelu(D) -> bf16       (mlp1)
// EPI 3: D + X -> routed fp32 d_out         (mlp2)
template <int KDIM, int EPI>
__global__ __launch_bounds__(256) void k_gemm(
    const unsigned short* __restrict__ A, const unsigned short* __restrict__ Wt,
    const float* __restrict__ bias, unsigned short* __restrict__ outb,
    float* __restrict__ X, float* __restrict__ out2, int Odim) {
    const int lane = threadIdx.x & 63;
    const int wv   = threadIdx.x >> 6;
    const int r16  = lane & 15;
    const int quad = lane >> 4;
    const int rowBase = blockIdx.x * 64 + wv * 16;   // 4 waves x 16 rows
    const int colBase = blockIdx.y * 64;             // 4 x 16-col tiles per wave
    const unsigned short* aPtr = A  + (long)(rowBase + r16) * KDIM + quad * 8;
    const unsigned short* bPtr = Wt + (long)(colBase + r16) * KDIM + quad * 8;
    f32x4 acc[4] = {};
    #pragma unroll 4
    for (int k0 = 0; k0 < KDIM; k0 += 32) {
        bf16x8 af = *reinterpret_cast<const bf16x8*>(aPtr + k0);
        #pragma unroll
        for (int c4 = 0; c4 < 4; ++c4) {
            bf16x8 bf = *reinterpret_cast<const bf16x8*>(bPtr + (long)c4 * 16 * KDIM + k0);
            acc[c4] = __builtin_amdgcn_mfma_f32_16x16x32_bf16(af, bf, acc[c4], 0, 0, 0);
        }
    }
    #pragma unroll
    for (int c4 = 0; c4 < 4; ++c4) {
        const int col = colBase + c4 * 16 + r16;     // D: col = lane&15
        const float bs = bias[col];
        #pragma unroll
        for (int r = 0; r < 4; ++r) {
            const int row = rowBase + quad * 4 + r;  // D: row = quad*4 + reg
            float v = acc[c4][r] + bs;
            if (EPI == 0) {
                outb[(long)row * Odim + col] = f2bf(v);
            } else if (EPI == 1) {
                const long xi = (long)row * CDIM + col;
                X[xi] = X[xi] + v;
            } else if (EPI == 2) {
                v = 0.5f * v * (1.0f + erff(v * 0.70710678118654752f));
                outb[(long)row * Odim + col] = f2bf(v);
            } else {
                const long xi = (long)row * CDIM + col;
                v += X[xi];
                const int mm = row / TOK;
                const int qq = row - mm * TOK;
                const long dst = (qq == 0)
                    ? (NCOUT + (long)mm * CDIM + col)                  // rt_out
                    : ((long)(mm * KTOK + qq - 1) * CDIM + col);       // data_out
                out2[dst] = v;
            }
        }
    }
}

// ---- attention: one block per m; fp32 softmax; RPE + mask ----
__global__ __launch_bounds__(256) void k_attn(
    const unsigned short* __restrict__ QKV,   // [T x 768] bf16 (q|k|v per token)
    const int* __restrict__ rel_pos,          // [M,32,32,3]
    const float* __restrict__ mask,           // [M,33,33]
    const float* __restrict__ rpe_table,      // [153,8]
    unsigned short* __restrict__ AO) {        // [T x 256] bf16
    const int m = blockIdx.x;
    const int tid = threadIdx.x;
    __shared__ float kS[TOK][CDIM];           // 33.8 KB
    __shared__ unsigned short vS[TOK][CDIM];  // 16.9 KB (bf16)
    __shared__ float rpeS[3 * RPE_NUM][HEADS + 1];  // pad to break bank aliasing
    for (int i = tid; i < 3 * RPE_NUM * HEADS; i += 256)
        rpeS[i >> 3][i & 7] = rpe_table[i];
    const unsigned short* base = QKV + (long)m * TOK * (3 * CDIM);
    for (int i = tid; i < TOK * CDIM; i += 256) {
        const int tok = i >> 8, cc = i & 255;
        kS[tok][cc] = bf2f(base[tok * 768 + 256 + cc]);
        vS[tok][cc] = base[tok * 768 + 512 + cc];
    }
    __syncthreads();
    for (int r = tid; r < HEADS * TOK; r += 256) {   // 264 (h,q) rows
        const int h = r / TOK, qq = r - h * TOK;
        float qv[DHEAD];
        const bf16x8* qp = reinterpret_cast<const bf16x8*>(base + qq * 768 + h * DHEAD);
        #pragma unroll
        for (int j = 0; j < 4; ++j) {
            bf16x8 q8 = qp[j];
            #pragma unroll
            for (int e = 0; e < 8; ++e)
                qv[j * 8 + e] = (float)q8[e] * 0.17677669529663688f;  // 1/sqrt(32)
        }
        float s[TOK];
        const float* mrow = mask + ((long)m * TOK + qq) * TOK;
        const int* rp_base = rel_pos + ((long)m * KTOK + (qq - 1)) * KTOK * 3;
        #pragma unroll
        for (int k2 = 0; k2 < TOK; ++k2) {
            float acc = 0.f;
            #pragma unroll
            for (int d = 0; d < DHEAD; ++d) acc += qv[d] * kS[k2][h * DHEAD + d];
            if (qq > 0 && k2 > 0) {
                const int* rpp = rp_base + (k2 - 1) * 3;
                #pragma unroll
                for (int a = 0; a < 3; ++a) {
                    int ix = rpp[a];
                    ix = (ix < -POS_BND) ? -POS_BND : (ix > POS_BND ? POS_BND : ix);
                    acc += rpeS[ix + POS_BND + a * RPE_NUM][h];
                }
            }
            s[k2] = acc + mrow[k2];
        }
        float mx = s[0];
        #pragma unroll
        for (int k2 = 1; k2 < TOK; ++k2) mx = fmaxf(mx, s[k2]);
        float sum = 0.f;
        #pragma unroll
        for (int k2 = 0; k2 < TOK; ++k2) { s[k2] = __expf(s[k2] - mx); sum += s[k2]; }
        const float inv = 1.f / sum;
        float o[DHEAD];
        #pragma unroll
        for (int d = 0; d < DHEAD; ++d) o[d] = 0.f;
        #pragma unroll
        for (int k2 = 0; k2 < TOK; ++k2) {
            const float p = s[k2] * inv;
            #pragma unroll
            for (int d = 0; d < DHEAD; ++d) o[d] += p * bf2f(vS[k2][h * DHEAD + d]);
        }
        unsigned short* op = AO + ((long)m * TOK + qq) * CDIM + h * DHEAD;
        #pragma unroll
        for (int d = 0; d < DHEAD; ++d) op[d] = f2bf(o[d]);
    }
}

extern "C" void kernel_launch(void* const* d_in, const int* in_sizes, int n_in,
                              void* d_out, int out_size, void* d_ws, size_t ws_size,
                              hipStream_t stream) {
    const float* data      = (const float*)d_in[0];
    const float* rt        = (const float*)d_in[1];
    const int*   neighbors = (const int*)d_in[2];
    const int*   rel_pos   = (const int*)d_in[3];
    const float* mask      = (const float*)d_in[4];
    const float* cpe_w     = (const float*)d_in[5];
    const float* cpe_scale = (const float*)d_in[6];
    const float* cpe_bias  = (const float*)d_in[7];
    const float* ln1_g     = (const float*)d_in[8];
    const float* ln1_b     = (const float*)d_in[9];
    const float* qkv_w     = (const float*)d_in[10];
    const float* qkv_b     = (const float*)d_in[11];
    const float* rpe_table = (const float*)d_in[12];
    const float* proj_w    = (const float*)d_in[13];
    const float* proj_b    = (const float*)d_in[14];
    const float* ln2_g     = (const float*)d_in[15];
    const float* ln2_b     = (const float*)d_in[16];
    const float* mlp_w1    = (const float*)d_in[17];
    const float* mlp_b1    = (const float*)d_in[18];
    const float* mlp_w2    = (const float*)d_in[19];
    const float* mlp_b2    = (const float*)d_in[20];
    float* out = (float*)d_out;

    // ---- workspace carve (≈0.97 GB) ----
    const long XB   = (long)TTOT * CDIM * 4;   // 276,824,064  X fp32 residual
    const long HB   = (long)TTOT * CDIM * 2;   // 138,412,032  H bf16 (h1/attn_out/h2)
    const long BIGB = (long)TTOT * HIDD * 2;   // 553,648,128  qkv then hid
    char* ws = (char*)d_ws;
    float*          X   = (float*)ws;
    unsigned short* Hb  = (unsigned short*)(ws + XB);
    unsigned short* BIG = (unsigned short*)(ws + XB + HB);
    unsigned short* WQ  = (unsigned short*)(ws + XB + HB + BIGB);
    unsigned short* WP  = WQ + 768 * 256;
    unsigned short* W1  = WP + 256 * 256;
    unsigned short* W2  = W1 + 1024 * 256;

    // weights -> bf16 transposed [O][K]
    k_wt<<<(768 * 256 + 255) / 256, 256, 0, stream>>>(qkv_w, WQ, 256, 768);
    k_wt<<<(256 * 256 + 255) / 256, 256, 0, stream>>>(proj_w, WP, 256, 256);
    k_wt<<<(1024 * 256 + 255) / 256, 256, 0, stream>>>(mlp_w1, W1, 256, 1024);
    k_wt<<<(1024 * 256 + 255) / 256, 256, 0, stream>>>(mlp_w2, W2, 1024, 256);

    // CPE + concat + LN1
    k_cpe_ln1<<<TTOT, 256, 0, stream>>>(data, rt, neighbors, cpe_w, cpe_scale,
                                        cpe_bias, ln1_g, ln1_b, X, Hb);
    // QKV
    k_gemm<256, 0><<<dim3(TTOT / 64, 12), 256, 0, stream>>>(Hb, WQ, qkv_b, BIG,
                                                            nullptr, nullptr, 768);
    // attention (writes attn_out into Hb; h1 is dead)
    k_attn<<<MDIM, 256, 0, stream>>>(BIG, rel_pos, mask, rpe_table, Hb);
    // proj + residual (in-place on X)
    k_gemm<256, 1><<<dim3(TTOT / 64, 4), 256, 0, stream>>>(Hb, WP, proj_b, nullptr,
                                                           X, nullptr, 256);
    // LN2 -> Hb
    k_ln<<<TTOT, 256, 0, stream>>>(X, ln2_g, ln2_b, Hb);
    // MLP1 + gelu -> BIG (qkv dead)
    k_gemm<256, 2><<<dim3(TTOT / 64, 16), 256, 0, stream>>>(Hb, W1, mlp_b1, BIG,
                                                            nullptr, nullptr, 1024);
    // MLP2 + residual -> routed d_out
    k_gemm<1024, 3><<<dim3(TTOT / 64, 4), 256, 0, stream>>>(BIG, W2, mlp_b2, nullptr,
                                                            X, out, 256);
}

// Round 2
// 3584.939 us; speedup vs baseline: 1.7026x; 1.7026x over previous
//
#include <hip/hip_runtime.h>

// ---- problem constants ----
#define MDIM 8192
#define KTOK 32
#define TOK 33            // K + G
#define CDIM 256
#define HEADS 8
#define DHEAD 32
#define NPTS (MDIM * KTOK)          // 262144
#define TTOT (MDIM * TOK)           // 270336
#define HIDD 1024
#define NEI 27
#define POS_BND 25
#define RPE_NUM 51                  // 2*POS_BND+1
#define NCOUT ((long)NPTS * CDIM)   // offset of rt_out in d_out
#define BK 32                       // GEMM K-step

typedef __bf16 bf16x8 __attribute__((ext_vector_type(8)));
typedef float f32x4 __attribute__((ext_vector_type(4)));

__device__ __forceinline__ unsigned short f2bf(float f) {
    unsigned u = __float_as_uint(f);
    u += 0x7FFFu + ((u >> 16) & 1u);      // round-to-nearest-even
    return (unsigned short)(u >> 16);
}
__device__ __forceinline__ float bf2f(unsigned short s) {
    return __uint_as_float(((unsigned)s) << 16);
}

// async global->LDS, 16B per lane; lds dst must be wave-uniform-base + lane*16
__device__ __forceinline__ void gld16(const unsigned short* g, unsigned short* l) {
    __builtin_amdgcn_global_load_lds(
        (const __attribute__((address_space(1))) unsigned int*)g,
        (__attribute__((address_space(3))) unsigned int*)l, 16, 0, 0);
}

// ---- weight transpose + bf16 cast: W[Kd][Od] -> Wt[Od][Kd] ----
__global__ void k_wt(const float* __restrict__ W, unsigned short* __restrict__ Wt,
                     int Kd, int Od) {
    int i = blockIdx.x * 256 + threadIdx.x;
    if (i >= Kd * Od) return;
    int o = i / Kd, k = i - o * Kd;
    Wt[i] = f2bf(W[(long)k * Od + o]);
}

// ---- CPE gather + concat(rt) + LN1 -> X (fp32 residual), H (bf16 LN'd) ----
__global__ __launch_bounds__(256) void k_cpe_ln1(
    const float* __restrict__ data, const float* __restrict__ rt,
    const int* __restrict__ neighbors,
    const float* __restrict__ cpe_w, const float* __restrict__ cpe_scale,
    const float* __restrict__ cpe_bias,
    const float* __restrict__ g, const float* __restrict__ b,
    float* __restrict__ X, unsigned short* __restrict__ H) {
    const int t = blockIdx.x;
    const int c = threadIdx.x;
    const int m = t / TOK;
    const int q = t - m * TOK;
    __shared__ int nb[NEI];
    __shared__ float sb[2][4];
    float val;
    if (q == 0) {                       // block-uniform branch
        val = rt[(long)m * CDIM + c];
    } else {
        const int n = m * KTOK + (q - 1);
        if (c < NEI) nb[c] = neighbors[(long)n * NEI + c];
        __syncthreads();
        float acc = 0.f;
        #pragma unroll
        for (int j = 0; j < NEI; ++j)
            acc += data[(long)nb[j] * CDIM + c] * cpe_w[j * CDIM + c];
        val = data[(long)n * CDIM + c] + acc * cpe_scale[c] + cpe_bias[c];
    }
    // block-wide mean/var over 256 channels (1 thread = 1 channel)
    float s = val, s2 = val * val;
    #pragma unroll
    for (int o = 32; o; o >>= 1) { s += __shfl_xor(s, o); s2 += __shfl_xor(s2, o); }
    const int wid = threadIdx.x >> 6;
    if ((threadIdx.x & 63) == 0) { sb[0][wid] = s; sb[1][wid] = s2; }
    __syncthreads();
    const float tot  = sb[0][0] + sb[0][1] + sb[0][2] + sb[0][3];
    const float tot2 = sb[1][0] + sb[1][1] + sb[1][2] + sb[1][3];
    const float mean = tot * (1.f / CDIM);
    const float var  = tot2 * (1.f / CDIM) - mean * mean;
    const float rs   = rsqrtf(var + 1e-5f);
    X[(long)t * CDIM + c] = val;
    H[(long)t * CDIM + c] = f2bf((val - mean) * rs * g[c] + b[c]);
}

// ---- LN2: X -> H (bf16) ----
__global__ __launch_bounds__(256) void k_ln(
    const float* __restrict__ X, const float* __restrict__ g,
    const float* __restrict__ b, unsigned short* __restrict__ H) {
    const int t = blockIdx.x;
    const int c = threadIdx.x;
    const float val = X[(long)t * CDIM + c];
    __shared__ float sb[2][4];
    float s = val, s2 = val * val;
    #pragma unroll
    for (int o = 32; o; o >>= 1) { s += __shfl_xor(s, o); s2 += __shfl_xor(s2, o); }
    const int wid = threadIdx.x >> 6;
    if ((threadIdx.x & 63) == 0) { sb[0][wid] = s; sb[1][wid] = s2; }
    __syncthreads();
    const float tot  = sb[0][0] + sb[0][1] + sb[0][2] + sb[0][3];
    const float tot2 = sb[1][0] + sb[1][1] + sb[1][2] + sb[1][3];
    const float mean = tot * (1.f / CDIM);
    const float var  = tot2 * (1.f / CDIM) - mean * mean;
    const float rs   = rsqrtf(var + 1e-5f);
    H[(long)t * CDIM + c] = f2bf((val - mean) * rs * g[c] + b[c]);
}

// ---- LDS-staged bf16 MFMA GEMM (m97 structure): 128x128 tile, BK=32 ----
// D[T x Odim] = A[T x KDIM] @ Wt[Odim x KDIM]^T + bias
// grid = (Odim/128, TTOT/128)  -- col tile fast so consecutive blocks share A
// EPI 0: store bf16            (qkv)
// EPI 1: X += D (fp32, in-place residual)   (proj)
// EPI 2: gelu(D) -> bf16       (mlp1)
// EPI 3: D + X -> routed fp32 d_out         (mlp2)
template <int KDIM, int EPI>
__global__ __launch_bounds__(256) void k_gemm(
    const unsigned short* __restrict__ A, const unsigned short* __restrict__ Wt,
    const float* __restrict__ bias, unsigned short* __restrict__ outb,
    float* __restrict__ X, float* __restrict__ out2, int Odim) {
    __shared__ __align__(16) unsigned short sA[128 * BK];   // 8 KB
    __shared__ __align__(16) unsigned short sB[128 * BK];   // 8 KB
    const int tid  = threadIdx.x;
    const int lane = tid & 63;
    const int wv   = tid >> 6;
    const int r16  = lane & 15;
    const int quad = lane >> 4;
    const int waveRow = (wv >> 1) * 64;
    const int waveCol = (wv & 1) * 64;
    const int rowBase = blockIdx.y * 128;
    const int colBase = blockIdx.x * 128;

    // staging: thread tid deposits 16B at LDS byte tid*16
    //   -> LDS row = tid>>2 (tile-row), k-elems (tid&3)*8
    const int sRow = tid >> 2;
    const int sK   = (tid & 3) * 8;
    const unsigned short* gA0 = A  + (long)(rowBase + sRow) * KDIM + sK;
    const unsigned short* gA1 = gA0 + (long)64 * KDIM;
    const unsigned short* gB0 = Wt + (long)(colBase + sRow) * KDIM + sK;
    const unsigned short* gB1 = gB0 + (long)64 * KDIM;
    unsigned short* lA0 = sA + tid * 8;
    unsigned short* lA1 = sA + 64 * BK + tid * 8;
    unsigned short* lB0 = sB + tid * 8;
    unsigned short* lB1 = sB + 64 * BK + tid * 8;

    f32x4 acc[4][4] = {};

    for (int k0 = 0; k0 < KDIM; k0 += BK) {
        gld16(gA0 + k0, lA0);
        gld16(gA1 + k0, lA1);
        gld16(gB0 + k0, lB0);
        gld16(gB1 + k0, lB1);
        __syncthreads();
        bf16x8 aF[4], bF[4];
        #pragma unroll
        for (int i = 0; i < 4; ++i)
            aF[i] = *reinterpret_cast<const bf16x8*>(
                        &sA[(waveRow + i * 16 + r16) * BK + quad * 8]);
        #pragma unroll
        for (int j = 0; j < 4; ++j)
            bF[j] = *reinterpret_cast<const bf16x8*>(
                        &sB[(waveCol + j * 16 + r16) * BK + quad * 8]);
        #pragma unroll
        for (int i = 0; i < 4; ++i)
            #pragma unroll
            for (int j = 0; j < 4; ++j)
                acc[i][j] = __builtin_amdgcn_mfma_f32_16x16x32_bf16(
                                aF[i], bF[j], acc[i][j], 0, 0, 0);
        __syncthreads();
    }

    // epilogue: D row = rowBase+waveRow+i*16+quad*4+r, col = colBase+waveCol+j*16+r16
    #pragma unroll
    for (int i = 0; i < 4; ++i) {
        #pragma unroll
        for (int r = 0; r < 4; ++r) {
            const int row = rowBase + waveRow + i * 16 + quad * 4 + r;
            int mm, qq;
            long dstBase = 0;
            if (EPI == 3) {
                mm = row / TOK;
                qq = row - mm * TOK;
                dstBase = (qq == 0) ? (NCOUT + (long)mm * CDIM)
                                    : ((long)(mm * KTOK + qq - 1) * CDIM);
            }
            #pragma unroll
            for (int j = 0; j < 4; ++j) {
                const int col = colBase + waveCol + j * 16 + r16;
                float v = acc[i][j][r] + bias[col];
                if (EPI == 0) {
                    outb[(long)row * Odim + col] = f2bf(v);
                } else if (EPI == 1) {
                    const long xi = (long)row * CDIM + col;
                    X[xi] = X[xi] + v;
                } else if (EPI == 2) {
                    v = 0.5f * v * (1.0f + erff(v * 0.70710678118654752f));
                    outb[(long)row * Odim + col] = f2bf(v);
                } else {
                    v += X[(long)row * CDIM + col];
                    out2[dstBase + col] = v;
                }
            }
        }
    }
}

// ---- attention: one block per m; fp32 softmax; RPE + mask ----
__global__ __launch_bounds__(256) void k_attn(
    const unsigned short* __restrict__ QKV,   // [T x 768] bf16 (q|k|v per token)
    const int* __restrict__ rel_pos,          // [M,32,32,3]
    const float* __restrict__ mask,           // [M,33,33]
    const float* __restrict__ rpe_table,      // [153,8]
    unsigned short* __restrict__ AO) {        // [T x 256] bf16
    const int m = blockIdx.x;
    const int tid = threadIdx.x;
    __shared__ float kS[TOK][CDIM];           // 33.8 KB
    __shared__ unsigned short vS[TOK][CDIM];  // 16.9 KB (bf16)
    __shared__ float rpeS[3 * RPE_NUM][HEADS + 1];  // pad to break bank aliasing
    for (int i = tid; i < 3 * RPE_NUM * HEADS; i += 256)
        rpeS[i >> 3][i & 7] = rpe_table[i];
    const unsigned short* base = QKV + (long)m * TOK * (3 * CDIM);
    for (int i = tid; i < TOK * CDIM; i += 256) {
        const int tok = i >> 8, cc = i & 255;
        kS[tok][cc] = bf2f(base[tok * 768 + 256 + cc]);
        vS[tok][cc] = base[tok * 768 + 512 + cc];
    }
    __syncthreads();
    for (int r = tid; r < HEADS * TOK; r += 256) {   // 264 (h,q) rows
        const int h = r / TOK, qq = r - h * TOK;
        float qv[DHEAD];
        const bf16x8* qp = reinterpret_cast<const bf16x8*>(base + qq * 768 + h * DHEAD);
        #pragma unroll
        for (int j = 0; j < 4; ++j) {
            bf16x8 q8 = qp[j];
            #pragma unroll
            for (int e = 0; e < 8; ++e)
                qv[j * 8 + e] = (float)q8[e] * 0.17677669529663688f;  // 1/sqrt(32)
        }
        float s[TOK];
        const float* mrow = mask + ((long)m * TOK + qq) * TOK;
        const int* rp_base = rel_pos + ((long)m * KTOK + (qq - 1)) * KTOK * 3;
        #pragma unroll
        for (int k2 = 0; k2 < TOK; ++k2) {
            float acc = 0.f;
            #pragma unroll
            for (int d = 0; d < DHEAD; ++d) acc += qv[d] * kS[k2][h * DHEAD + d];
            if (qq > 0 && k2 > 0) {
                const int* rpp = rp_base + (k2 - 1) * 3;
                #pragma unroll
                for (int a = 0; a < 3; ++a) {
                    int ix = rpp[a];
                    ix = (ix < -POS_BND) ? -POS_BND : (ix > POS_BND ? POS_BND : ix);
                    acc += rpeS[ix + POS_BND + a * RPE_NUM][h];
                }
            }
            s[k2] = acc + mrow[k2];
        }
        float mx = s[0];
        #pragma unroll
        for (int k2 = 1; k2 < TOK; ++k2) mx = fmaxf(mx, s[k2]);
        float sum = 0.f;
        #pragma unroll
        for (int k2 = 0; k2 < TOK; ++k2) { s[k2] = __expf(s[k2] - mx); sum += s[k2]; }
        const float inv = 1.f / sum;
        float o[DHEAD];
        #pragma unroll
        for (int d = 0; d < DHEAD; ++d) o[d] = 0.f;
        #pragma unroll
        for (int k2 = 0; k2 < TOK; ++k2) {
            const float p = s[k2] * inv;
            #pragma unroll
            for (int d = 0; d < DHEAD; ++d) o[d] += p * bf2f(vS[k2][h * DHEAD + d]);
        }
        unsigned short* op = AO + ((long)m * TOK + qq) * CDIM + h * DHEAD;
        #pragma unroll
        for (int d = 0; d < DHEAD; ++d) op[d] = f2bf(o[d]);
    }
}

extern "C" void kernel_launch(void* const* d_in, const int* in_sizes, int n_in,
                              void* d_out, int out_size, void* d_ws, size_t ws_size,
                              hipStream_t stream) {
    const float* data      = (const float*)d_in[0];
    const float* rt        = (const float*)d_in[1];
    const int*   neighbors = (const int*)d_in[2];
    const int*   rel_pos   = (const int*)d_in[3];
    const float* mask      = (const float*)d_in[4];
    const float* cpe_w     = (const float*)d_in[5];
    const float* cpe_scale = (const float*)d_in[6];
    const float* cpe_bias  = (const float*)d_in[7];
    const float* ln1_g     = (const float*)d_in[8];
    const float* ln1_b     = (const float*)d_in[9];
    const float* qkv_w     = (const float*)d_in[10];
    const float* qkv_b     = (const float*)d_in[11];
    const float* rpe_table = (const float*)d_in[12];
    const float* proj_w    = (const float*)d_in[13];
    const float* proj_b    = (const float*)d_in[14];
    const float* ln2_g     = (const float*)d_in[15];
    const float* ln2_b     = (const float*)d_in[16];
    const float* mlp_w1    = (const float*)d_in[17];
    const float* mlp_b1    = (const float*)d_in[18];
    const float* mlp_w2    = (const float*)d_in[19];
    const float* mlp_b2    = (const float*)d_in[20];
    float* out = (float*)d_out;

    // ---- workspace carve (≈0.97 GB) ----
    const long XB   = (long)TTOT * CDIM * 4;   // X fp32 residual
    const long HB   = (long)TTOT * CDIM * 2;   // H bf16 (h1/attn_out/h2)
    const long BIGB = (long)TTOT * HIDD * 2;   // qkv then hid
    char* ws = (char*)d_ws;
    float*          X   = (float*)ws;
    unsigned short* Hb  = (unsigned short*)(ws + XB);
    unsigned short* BIG = (unsigned short*)(ws + XB + HB);
    unsigned short* WQ  = (unsigned short*)(ws + XB + HB + BIGB);
    unsigned short* WP  = WQ + 768 * 256;
    unsigned short* W1  = WP + 256 * 256;
    unsigned short* W2  = W1 + 1024 * 256;

    // weights -> bf16 transposed [O][K]
    k_wt<<<(768 * 256 + 255) / 256, 256, 0, stream>>>(qkv_w, WQ, 256, 768);
    k_wt<<<(256 * 256 + 255) / 256, 256, 0, stream>>>(proj_w, WP, 256, 256);
    k_wt<<<(1024 * 256 + 255) / 256, 256, 0, stream>>>(mlp_w1, W1, 256, 1024);
    k_wt<<<(1024 * 256 + 255) / 256, 256, 0, stream>>>(mlp_w2, W2, 1024, 256);

    // CPE + concat + LN1
    k_cpe_ln1<<<TTOT, 256, 0, stream>>>(data, rt, neighbors, cpe_w, cpe_scale,
                                        cpe_bias, ln1_g, ln1_b, X, Hb);
    // QKV
    k_gemm<256, 0><<<dim3(768 / 128, TTOT / 128), 256, 0, stream>>>(
        Hb, WQ, qkv_b, BIG, nullptr, nullptr, 768);
    // attention (writes attn_out into Hb; h1 is dead)
    k_attn<<<MDIM, 256, 0, stream>>>(BIG, rel_pos, mask, rpe_table, Hb);
    // proj + residual (in-place on X)
    k_gemm<256, 1><<<dim3(256 / 128, TTOT / 128), 256, 0, stream>>>(
        Hb, WP, proj_b, nullptr, X, nullptr, 256);
    // LN2 -> Hb
    k_ln<<<TTOT, 256, 0, stream>>>(X, ln2_g, ln2_b, Hb);
    // MLP1 + gelu -> BIG (qkv dead)
    k_gemm<256, 2><<<dim3(1024 / 128, TTOT / 128), 256, 0, stream>>>(
        Hb, W1, mlp_b1, BIG, nullptr, nullptr, 1024);
    // MLP2 + residual -> routed d_out
    k_gemm<1024, 3><<<dim3(256 / 128, TTOT / 128), 256, 0, stream>>>(
        BIG, W2, mlp_b2, nullptr, X, out, 256);
}